// Round 1
// baseline (751.604 us; speedup 1.0000x reference)
//
#include <hip/hip_runtime.h>
#include <math.h>

typedef float v2f __attribute__((ext_vector_type(2)));

namespace {

constexpr int C_DIM = 4;
constexpr int D_DIM = 64;
constexpr int H_DIM = 160;
constexpr int W_DIM = 160;

constexpr int TH = 20;
constexpr int TW = 20;
constexpr int HALO = 5;
constexpr int EH = 30;
constexpr int EW = 30;
constexpr int XST = 31;          // v2f stride of xy rows (odd)
constexpr int MST = 21;          // float4 stride of mid rows (odd)
constexpr int NPIX = EH * EW;    // 900

constexpr int TILES_W = 8;       // 160/20
constexpr int TPC = 64;          // 8x8 tiles per (b,c)
constexpr int D_SPLIT = 2;       // split D into 2 chunks -> 4 blocks/CU
constexpr int DCH = D_DIM / D_SPLIT;               // 32 output slices/block
constexpr int NBLOCKS = D_SPLIT * 2 * C_DIM * TPC; // 1024 = 4 blocks/CU

constexpr float C1f = 1e-4f;
constexpr float C2f = 9e-4f;
constexpr float INV_N = 1.0f / (2.0f * 64.0f * 160.0f * 160.0f);

struct GW { float g[11]; };

}  // namespace

__global__ void finalize_kernel(const float* __restrict__ partial,
                                float* __restrict__ out) {
    const int tid = threadIdx.x;
    const int c = tid >> 6;        // one wave per channel
    const int lane = tid & 63;     // lane == tile index (TPC == 64)
    float s = 0.0f;
#pragma unroll
    for (int r = 0; r < D_SPLIT * 2; ++r)
        s += partial[(r * C_DIM + c) * TPC + lane];
#pragma unroll
    for (int off = 32; off > 0; off >>= 1) s += __shfl_down(s, off, 64);
    if (lane == 0 && c < C_DIM) out[c] = 1.0f - s * INV_N;
}

__global__ __launch_bounds__(256, 4) void ssim3d_kernel(
    const float* __restrict__ img1, const float* __restrict__ img2,
    float* __restrict__ partial, GW gwp) {

    const int bid = blockIdx.x;
    const int tile = bid % TPC;
    const int c = (bid / TPC) % C_DIM;
    const int rest = bid / (TPC * C_DIM);
    const int b = rest & 1;
    const int dh = rest >> 1;
    const int h0 = (tile / TILES_W) * TH;
    const int w0 = (tile % TILES_W) * TW;

    // D chunk: outputs d in [d_lo, d_lo+DCH). Staged slices [s_base, s_hi],
    // s_base rounded down to a multiple of 4 so slice phase u == s mod 4
    // (window slot arithmetic depends on it).
    const int d_lo = dh * DCH;
    const int s_base = (d_lo == 0) ? 0 : ((d_lo - HALO) & ~3);
    const int s_hi = min(D_DIM - 1, d_lo + DCH - 1 + HALO);
    const bool has_tail = (d_lo + DCH == D_DIM);  // top zero-pad epilogue

    const long planeHW = (long)H_DIM * W_DIM;
    const long volbase = (long)(b * C_DIM + c) * D_DIM * planeHW;
    const long org = volbase + (long)(h0 - HALO) * W_DIM + (w0 - HALO);
    const float* __restrict__ p1 = img1 + org;
    const float* __restrict__ p2 = img2 + org;

    const bool interior = (h0 >= HALO) && (h0 + TH + HALO <= H_DIM) &&
                          (w0 >= HALO) && (w0 + TW + HALO <= W_DIM);

    // ---- LDS (both stages double-buffered -> 1 barrier per slice) ----
    __shared__ v2f    xy[2][EH][XST];    // interleaved (x,y), b64
    __shared__ float4 mid[2][EH][MST];   // W-conv (sx,sy | sq,sp), b128
    __shared__ float  rbuf[4];

    const int tid = threadIdx.x;

    // ---- staging decode (4 positions/thread, 900 px) ----
    int hh_[4], ww_[4], off_[4];
    bool live_[4], ok_[4];
#pragma unroll
    for (int k = 0; k < 4; ++k) {
        const int e = tid + k * 256;
        live_[k] = (e < NPIX);
        const int hh = e / EW;
        const int ww = e - hh * EW;
        hh_[k] = hh; ww_[k] = ww;
        off_[k] = hh * W_DIM + ww;
        const int gh = h0 - HALO + hh;
        const int gw = w0 - HALO + ww;
        ok_[k] = ((unsigned)gh < (unsigned)H_DIM) &&
                 ((unsigned)gw < (unsigned)W_DIM);
    }

    auto fetch_slice = [&](int s, v2f lv[4]) {
        const long sb = (long)s * planeHW;
#pragma unroll
        for (int k = 0; k < 4; ++k) {
            lv[k] = (v2f){0.0f, 0.0f};
            if (live_[k] && (interior || ok_[k])) {
                const long gi = sb + off_[k];
                lv[k].x = p1[gi];
                lv[k].y = p2[gi];
            }
        }
    };
    auto commit_slice = [&](int buf, const v2f lv[4]) {
#pragma unroll
        for (int k = 0; k < 4; ++k)
            if (live_[k]) xy[buf][hh_[k]][ww_[k]] = lv[k];
    };

    // ---- wconv: 150 workers (rows fastest), 4 outputs each, 14-tap stream
    const bool wactive = (tid < 150);
    const int whh = tid % 30;
    const int wg  = (tid / 30) * 4;   // 0,4,8,12,16

    auto wconv = [&](int cur) {
        v2f a0 = {0.f,0.f}, a1 = {0.f,0.f}, a2 = {0.f,0.f}, a3 = {0.f,0.f};
        v2f q0 = {0.f,0.f}, q1 = {0.f,0.f}, q2 = {0.f,0.f}, q3 = {0.f,0.f};
#pragma unroll
        for (int t = 0; t < 14; ++t) {
            const v2f xv = xy[cur][whh][wg + t];
            v2f qp;
            qp.x = fmaf(xv.x, xv.x, xv.y * xv.y);  // x^2 + y^2
            qp.y = xv.x * xv.y;                    // x*y
            if (t <= 10) {
                const v2f g2 = {gwp.g[t], gwp.g[t]};
                a0 = __builtin_elementwise_fma(g2, xv, a0);
                q0 = __builtin_elementwise_fma(g2, qp, q0);
            }
            if (t >= 1 && t <= 11) {
                const v2f g2 = {gwp.g[t-1], gwp.g[t-1]};
                a1 = __builtin_elementwise_fma(g2, xv, a1);
                q1 = __builtin_elementwise_fma(g2, qp, q1);
            }
            if (t >= 2 && t <= 12) {
                const v2f g2 = {gwp.g[t-2], gwp.g[t-2]};
                a2 = __builtin_elementwise_fma(g2, xv, a2);
                q2 = __builtin_elementwise_fma(g2, qp, q2);
            }
            if (t >= 3) {
                const v2f g2 = {gwp.g[t-3], gwp.g[t-3]};
                a3 = __builtin_elementwise_fma(g2, xv, a3);
                q3 = __builtin_elementwise_fma(g2, qp, q3);
            }
        }
        mid[cur][whh][wg]     = make_float4(a0.x, a0.y, q0.x, q0.y);
        mid[cur][whh][wg + 1] = make_float4(a1.x, a1.y, q1.x, q1.y);
        mid[cur][whh][wg + 2] = make_float4(a2.x, a2.y, q2.x, q2.y);
        mid[cur][whh][wg + 3] = make_float4(a3.x, a3.y, q3.x, q3.y);
    };

    // ---- hconv: 200 workers, 2 H-outputs each (rows h, h+1), 12-tap stream
    const bool hworker = (tid < 200);
    const int hw = tid % 20;          // w position
    const int hb = (tid / 20) * 2;    // h base: 0,2,..,18

    float accum = 0.0f;
    auto ssim_add = [&](v2f mxy, v2f mqp) {
        const float m1 = mxy.x, m2 = mxy.y;
        const float q = mqp.x, pp = mqp.y;
        const float m1s = m1 * m1;
        const float m2s = m2 * m2;
        const float m12 = m1 * m2;
        const float spp = q - m1s - m2s;
        const float s12 = pp - m12;
        const float num = (2.0f * m12 + C1f) * (2.0f * s12 + C2f);
        const float den = (m1s + m2s + C1f) * (spp + C2f);
        accum = fmaf(num, __builtin_amdgcn_rcpf(den), accum);
    };

    // two D-windows (outputs h=hb and h=hb+1): 14 slots, insert at 10+u,
    // consume over [u..u+10], shift by 4 per 4 slices. Static indices only.
    v2f w0xy[14], w0qp[14], w1xy[14], w1qp[14];
#pragma unroll
    for (int i = 0; i < 14; ++i) {
        w0xy[i] = (v2f){0.f, 0.f}; w0qp[i] = (v2f){0.f, 0.f};
        w1xy[i] = (v2f){0.f, 0.f}; w1qp[i] = (v2f){0.f, 0.f};
    }

    // prologue: slice s_base -> xy[0]  (s_base % 4 == 0 -> buffer 0)
    {
        v2f lv[4];
        fetch_slice(s_base, lv);
        commit_slice(0, lv);
    }
    __syncthreads();

    for (int sb = s_base; sb <= s_hi; sb += 4) {   // sb mult of 4 -> s&1==u&1
#pragma unroll
        for (int u = 0; u < 4; ++u) {
            const int s = sb + u;
            if (s > s_hi) break;          // block-uniform
            v2f lv[4];
            const bool have_next = (s + 1 <= s_hi);
            if (have_next) fetch_slice(s + 1, lv);
            if (wactive) wconv(u & 1);
            if (have_next) commit_slice((u + 1) & 1, lv);
            __syncthreads();
            if (hworker) {
                // H-conv, 2 outputs from 12 b128 reads
                v2f z0x = {0.f,0.f}, z0q = {0.f,0.f};
                v2f z1x = {0.f,0.f}, z1q = {0.f,0.f};
#pragma unroll
                for (int t = 0; t < 12; ++t) {
                    const float4 m = mid[u & 1][hb + t][hw];
                    const v2f ma = {m.x, m.y};
                    const v2f mb = {m.z, m.w};
                    if (t <= 10) {
                        const v2f g2 = {gwp.g[t], gwp.g[t]};
                        z0x = __builtin_elementwise_fma(g2, ma, z0x);
                        z0q = __builtin_elementwise_fma(g2, mb, z0q);
                    }
                    if (t >= 1) {
                        const v2f g2 = {gwp.g[t-1], gwp.g[t-1]};
                        z1x = __builtin_elementwise_fma(g2, ma, z1x);
                        z1q = __builtin_elementwise_fma(g2, mb, z1q);
                    }
                }
                w0xy[10 + u] = z0x; w0qp[10 + u] = z0q;
                w1xy[10 + u] = z1x; w1qp[10 + u] = z1q;
                if (s >= d_lo + HALO) {   // output d = s-5 (>= d_lo)
                    v2f mx0 = {0.f,0.f}, mq0 = {0.f,0.f};
                    v2f mx1 = {0.f,0.f}, mq1 = {0.f,0.f};
#pragma unroll
                    for (int t = 0; t < 11; ++t) {
                        const v2f g2 = {gwp.g[t], gwp.g[t]};
                        mx0 = __builtin_elementwise_fma(g2, w0xy[u + t], mx0);
                        mq0 = __builtin_elementwise_fma(g2, w0qp[u + t], mq0);
                        mx1 = __builtin_elementwise_fma(g2, w1xy[u + t], mx1);
                        mq1 = __builtin_elementwise_fma(g2, w1qp[u + t], mq1);
                    }
                    ssim_add(mx0, mq0);
                    ssim_add(mx1, mq1);
                }
            }
        }
        if (hworker) {
            // shift both windows by 4
#pragma unroll
            for (int k = 0; k < 10; ++k) {
                w0xy[k] = w0xy[k + 4]; w0qp[k] = w0qp[k + 4];
                w1xy[k] = w1xy[k + 4]; w1qp[k] = w1qp[k + 4];
            }
        }
    }

    // epilogue (only the chunk reaching d=D_DIM-1): outputs d = 59..63;
    // windows hold slices 54+k at slot k (0..9)
    if (has_tail && hworker) {
#pragma unroll
        for (int i = 10; i < 14; ++i) {
            w0xy[i] = (v2f){0.f, 0.f}; w0qp[i] = (v2f){0.f, 0.f};
            w1xy[i] = (v2f){0.f, 0.f}; w1qp[i] = (v2f){0.f, 0.f};
        }
#pragma unroll
        for (int u2 = 0; u2 < 5; ++u2) {   // output d = 59 + u2
            v2f mx0 = {0.f,0.f}, mq0 = {0.f,0.f};
            v2f mx1 = {0.f,0.f}, mq1 = {0.f,0.f};
#pragma unroll
            for (int t = 0; t < 11; ++t) {
                if (u2 + t <= 13) {        // static guard; dropped taps zero
                    const v2f g2 = {gwp.g[t], gwp.g[t]};
                    mx0 = __builtin_elementwise_fma(g2, w0xy[u2 + t], mx0);
                    mq0 = __builtin_elementwise_fma(g2, w0qp[u2 + t], mq0);
                    mx1 = __builtin_elementwise_fma(g2, w1xy[u2 + t], mx1);
                    mq1 = __builtin_elementwise_fma(g2, w1qp[u2 + t], mq1);
                }
            }
            ssim_add(mx0, mq0);
            ssim_add(mx1, mq1);
        }
    }

    // ---- block reduction -> one partial per block ----
#pragma unroll
    for (int off = 32; off > 0; off >>= 1) accum += __shfl_down(accum, off, 64);
    const int wave = tid >> 6;
    const int lane = tid & 63;
    if (lane == 0) rbuf[wave] = accum;
    __syncthreads();
    if (tid == 0) partial[bid] = rbuf[0] + rbuf[1] + rbuf[2] + rbuf[3];
}

extern "C" void kernel_launch(void* const* d_in, const int* in_sizes, int n_in,
                              void* d_out, int out_size, void* d_ws, size_t ws_size,
                              hipStream_t stream) {
    const float* img1 = (const float*)d_in[0];
    const float* img2 = (const float*)d_in[1];
    float* out = (float*)d_out;
    float* partial = (float*)d_ws;   // NBLOCKS floats (4 KB)

    GW gw;
    {
        double gd[11];
        double ssum = 0.0;
        for (int i = 0; i < 11; ++i) {
            const double t = (double)(i - 5);
            gd[i] = exp(-(t * t) / 4.5);
            ssum += gd[i];
        }
        for (int i = 0; i < 11; ++i) gw.g[i] = (float)(gd[i] / ssum);
    }

    ssim3d_kernel<<<NBLOCKS, 256, 0, stream>>>(img1, img2, partial, gw);
    finalize_kernel<<<1, 256, 0, stream>>>(partial, out);
}

// Round 2
// 225.998 us; speedup vs baseline: 3.3257x; 3.3257x over previous
//
#include <hip/hip_runtime.h>
#include <math.h>

typedef float v2f __attribute__((ext_vector_type(2)));

namespace {

constexpr int C_DIM = 4;
constexpr int D_DIM = 64;
constexpr int H_DIM = 160;
constexpr int W_DIM = 160;

constexpr int TH = 20;
constexpr int TW = 20;
constexpr int HALO = 5;
constexpr int EH = 30;
constexpr int EW = 30;
constexpr int XST = 31;          // v2f stride of xy rows (odd)
constexpr int MST = 21;          // float4 stride of mid rows (odd)
constexpr int NPIX = EH * EW;    // 900

constexpr int TILES_W = 8;       // 160/20
constexpr int TPC = 64;          // 8x8 tiles per (b,c)
constexpr int D_SPLIT = 2;       // split D into 2 chunks -> 4 blocks/CU
constexpr int DCH = D_DIM / D_SPLIT;               // 32 output slices/block
constexpr int NBLOCKS = D_SPLIT * 2 * C_DIM * TPC; // 1024 = 4 blocks/CU

constexpr float C1f = 1e-4f;
constexpr float C2f = 9e-4f;
constexpr float INV_N = 1.0f / (2.0f * 64.0f * 160.0f * 160.0f);

struct GW { float g[11]; };

}  // namespace

__global__ void finalize_kernel(const float* __restrict__ partial,
                                float* __restrict__ out) {
    const int tid = threadIdx.x;
    const int c = tid >> 6;        // one wave per channel
    const int lane = tid & 63;     // lane == tile index (TPC == 64)
    float s = 0.0f;
#pragma unroll
    for (int r = 0; r < D_SPLIT * 2; ++r)
        s += partial[(r * C_DIM + c) * TPC + lane];
#pragma unroll
    for (int off = 32; off > 0; off >>= 1) s += __shfl_down(s, off, 64);
    if (lane == 0 && c < C_DIM) out[c] = 1.0f - s * INV_N;
}

// NOTE: __launch_bounds__(256,2) only CAPS VGPR at 256 — the kernel
// naturally allocates ~116 VGPR -> 4 waves/SIMD -> 4 blocks/CU with the
// 1024-block grid. Do NOT raise the 2nd arg: (256,4) capped VGPR at 64,
// spilled the per-thread D-windows to scratch (2.5 GB HBM traffic, 5x slower).
__global__ __launch_bounds__(256, 2) void ssim3d_kernel(
    const float* __restrict__ img1, const float* __restrict__ img2,
    float* __restrict__ partial, GW gwp) {

    const int bid = blockIdx.x;
    const int tile = bid % TPC;
    const int c = (bid / TPC) % C_DIM;
    const int rest = bid / (TPC * C_DIM);
    const int b = rest & 1;
    const int dh = rest >> 1;
    const int h0 = (tile / TILES_W) * TH;
    const int w0 = (tile % TILES_W) * TW;

    // D chunk: outputs d in [d_lo, d_lo+DCH). Staged slices [s_base, s_hi],
    // s_base rounded down to a multiple of 4 so slice phase u == s mod 4
    // (window slot arithmetic depends on it).
    const int d_lo = dh * DCH;
    const int s_base = (d_lo == 0) ? 0 : ((d_lo - HALO) & ~3);
    const int s_hi = min(D_DIM - 1, d_lo + DCH - 1 + HALO);
    const bool has_tail = (d_lo + DCH == D_DIM);  // top zero-pad epilogue

    const long planeHW = (long)H_DIM * W_DIM;
    const long volbase = (long)(b * C_DIM + c) * D_DIM * planeHW;
    const long org = volbase + (long)(h0 - HALO) * W_DIM + (w0 - HALO);
    const float* __restrict__ p1 = img1 + org;
    const float* __restrict__ p2 = img2 + org;

    const bool interior = (h0 >= HALO) && (h0 + TH + HALO <= H_DIM) &&
                          (w0 >= HALO) && (w0 + TW + HALO <= W_DIM);

    // ---- LDS (both stages double-buffered -> 1 barrier per slice) ----
    __shared__ v2f    xy[2][EH][XST];    // interleaved (x,y), b64
    __shared__ float4 mid[2][EH][MST];   // W-conv (sx,sy | sq,sp), b128
    __shared__ float  rbuf[4];

    const int tid = threadIdx.x;

    // ---- staging decode (4 positions/thread, 900 px) ----
    int hh_[4], ww_[4], off_[4];
    bool live_[4], ok_[4];
#pragma unroll
    for (int k = 0; k < 4; ++k) {
        const int e = tid + k * 256;
        live_[k] = (e < NPIX);
        const int hh = e / EW;
        const int ww = e - hh * EW;
        hh_[k] = hh; ww_[k] = ww;
        off_[k] = hh * W_DIM + ww;
        const int gh = h0 - HALO + hh;
        const int gw = w0 - HALO + ww;
        ok_[k] = ((unsigned)gh < (unsigned)H_DIM) &&
                 ((unsigned)gw < (unsigned)W_DIM);
    }

    auto fetch_slice = [&](int s, v2f lv[4]) {
        const long sb = (long)s * planeHW;
#pragma unroll
        for (int k = 0; k < 4; ++k) {
            lv[k] = (v2f){0.0f, 0.0f};
            if (live_[k] && (interior || ok_[k])) {
                const long gi = sb + off_[k];
                lv[k].x = p1[gi];
                lv[k].y = p2[gi];
            }
        }
    };
    auto commit_slice = [&](int buf, const v2f lv[4]) {
#pragma unroll
        for (int k = 0; k < 4; ++k)
            if (live_[k]) xy[buf][hh_[k]][ww_[k]] = lv[k];
    };

    // ---- wconv: 150 workers (rows fastest), 4 outputs each, 14-tap stream
    const bool wactive = (tid < 150);
    const int whh = tid % 30;
    const int wg  = (tid / 30) * 4;   // 0,4,8,12,16

    auto wconv = [&](int cur) {
        v2f a0 = {0.f,0.f}, a1 = {0.f,0.f}, a2 = {0.f,0.f}, a3 = {0.f,0.f};
        v2f q0 = {0.f,0.f}, q1 = {0.f,0.f}, q2 = {0.f,0.f}, q3 = {0.f,0.f};
#pragma unroll
        for (int t = 0; t < 14; ++t) {
            const v2f xv = xy[cur][whh][wg + t];
            v2f qp;
            qp.x = fmaf(xv.x, xv.x, xv.y * xv.y);  // x^2 + y^2
            qp.y = xv.x * xv.y;                    // x*y
            if (t <= 10) {
                const v2f g2 = {gwp.g[t], gwp.g[t]};
                a0 = __builtin_elementwise_fma(g2, xv, a0);
                q0 = __builtin_elementwise_fma(g2, qp, q0);
            }
            if (t >= 1 && t <= 11) {
                const v2f g2 = {gwp.g[t-1], gwp.g[t-1]};
                a1 = __builtin_elementwise_fma(g2, xv, a1);
                q1 = __builtin_elementwise_fma(g2, qp, q1);
            }
            if (t >= 2 && t <= 12) {
                const v2f g2 = {gwp.g[t-2], gwp.g[t-2]};
                a2 = __builtin_elementwise_fma(g2, xv, a2);
                q2 = __builtin_elementwise_fma(g2, qp, q2);
            }
            if (t >= 3) {
                const v2f g2 = {gwp.g[t-3], gwp.g[t-3]};
                a3 = __builtin_elementwise_fma(g2, xv, a3);
                q3 = __builtin_elementwise_fma(g2, qp, q3);
            }
        }
        mid[cur][whh][wg]     = make_float4(a0.x, a0.y, q0.x, q0.y);
        mid[cur][whh][wg + 1] = make_float4(a1.x, a1.y, q1.x, q1.y);
        mid[cur][whh][wg + 2] = make_float4(a2.x, a2.y, q2.x, q2.y);
        mid[cur][whh][wg + 3] = make_float4(a3.x, a3.y, q3.x, q3.y);
    };

    // ---- hconv: 200 workers, 2 H-outputs each (rows h, h+1), 12-tap stream
    const bool hworker = (tid < 200);
    const int hw = tid % 20;          // w position
    const int hb = (tid / 20) * 2;    // h base: 0,2,..,18

    float accum = 0.0f;
    auto ssim_add = [&](v2f mxy, v2f mqp) {
        const float m1 = mxy.x, m2 = mxy.y;
        const float q = mqp.x, pp = mqp.y;
        const float m1s = m1 * m1;
        const float m2s = m2 * m2;
        const float m12 = m1 * m2;
        const float spp = q - m1s - m2s;
        const float s12 = pp - m12;
        const float num = (2.0f * m12 + C1f) * (2.0f * s12 + C2f);
        const float den = (m1s + m2s + C1f) * (spp + C2f);
        accum = fmaf(num, __builtin_amdgcn_rcpf(den), accum);
    };

    // two D-windows (outputs h=hb and h=hb+1): 14 slots, insert at 10+u,
    // consume over [u..u+10], shift by 4 per 4 slices. Static indices only.
    v2f w0xy[14], w0qp[14], w1xy[14], w1qp[14];
#pragma unroll
    for (int i = 0; i < 14; ++i) {
        w0xy[i] = (v2f){0.f, 0.f}; w0qp[i] = (v2f){0.f, 0.f};
        w1xy[i] = (v2f){0.f, 0.f}; w1qp[i] = (v2f){0.f, 0.f};
    }

    // prologue: slice s_base -> xy[0]  (s_base % 4 == 0 -> buffer 0)
    {
        v2f lv[4];
        fetch_slice(s_base, lv);
        commit_slice(0, lv);
    }
    __syncthreads();

    for (int sb = s_base; sb <= s_hi; sb += 4) {   // sb mult of 4 -> s&1==u&1
#pragma unroll
        for (int u = 0; u < 4; ++u) {
            const int s = sb + u;
            if (s > s_hi) break;          // block-uniform
            v2f lv[4];
            const bool have_next = (s + 1 <= s_hi);
            if (have_next) fetch_slice(s + 1, lv);
            if (wactive) wconv(u & 1);
            if (have_next) commit_slice((u + 1) & 1, lv);
            __syncthreads();
            if (hworker) {
                // H-conv, 2 outputs from 12 b128 reads
                v2f z0x = {0.f,0.f}, z0q = {0.f,0.f};
                v2f z1x = {0.f,0.f}, z1q = {0.f,0.f};
#pragma unroll
                for (int t = 0; t < 12; ++t) {
                    const float4 m = mid[u & 1][hb + t][hw];
                    const v2f ma = {m.x, m.y};
                    const v2f mb = {m.z, m.w};
                    if (t <= 10) {
                        const v2f g2 = {gwp.g[t], gwp.g[t]};
                        z0x = __builtin_elementwise_fma(g2, ma, z0x);
                        z0q = __builtin_elementwise_fma(g2, mb, z0q);
                    }
                    if (t >= 1) {
                        const v2f g2 = {gwp.g[t-1], gwp.g[t-1]};
                        z1x = __builtin_elementwise_fma(g2, ma, z1x);
                        z1q = __builtin_elementwise_fma(g2, mb, z1q);
                    }
                }
                w0xy[10 + u] = z0x; w0qp[10 + u] = z0q;
                w1xy[10 + u] = z1x; w1qp[10 + u] = z1q;
                if (s >= d_lo + HALO) {   // output d = s-5 (>= d_lo)
                    v2f mx0 = {0.f,0.f}, mq0 = {0.f,0.f};
                    v2f mx1 = {0.f,0.f}, mq1 = {0.f,0.f};
#pragma unroll
                    for (int t = 0; t < 11; ++t) {
                        const v2f g2 = {gwp.g[t], gwp.g[t]};
                        mx0 = __builtin_elementwise_fma(g2, w0xy[u + t], mx0);
                        mq0 = __builtin_elementwise_fma(g2, w0qp[u + t], mq0);
                        mx1 = __builtin_elementwise_fma(g2, w1xy[u + t], mx1);
                        mq1 = __builtin_elementwise_fma(g2, w1qp[u + t], mq1);
                    }
                    ssim_add(mx0, mq0);
                    ssim_add(mx1, mq1);
                }
            }
        }
        if (hworker) {
            // shift both windows by 4
#pragma unroll
            for (int k = 0; k < 10; ++k) {
                w0xy[k] = w0xy[k + 4]; w0qp[k] = w0qp[k + 4];
                w1xy[k] = w1xy[k + 4]; w1qp[k] = w1qp[k + 4];
            }
        }
    }

    // epilogue (only the chunk reaching d=D_DIM-1): outputs d = 59..63;
    // windows hold slices 54+k at slot k (0..9)
    if (has_tail && hworker) {
#pragma unroll
        for (int i = 10; i < 14; ++i) {
            w0xy[i] = (v2f){0.f, 0.f}; w0qp[i] = (v2f){0.f, 0.f};
            w1xy[i] = (v2f){0.f, 0.f}; w1qp[i] = (v2f){0.f, 0.f};
        }
#pragma unroll
        for (int u2 = 0; u2 < 5; ++u2) {   // output d = 59 + u2
            v2f mx0 = {0.f,0.f}, mq0 = {0.f,0.f};
            v2f mx1 = {0.f,0.f}, mq1 = {0.f,0.f};
#pragma unroll
            for (int t = 0; t < 11; ++t) {
                if (u2 + t <= 13) {        // static guard; dropped taps zero
                    const v2f g2 = {gwp.g[t], gwp.g[t]};
                    mx0 = __builtin_elementwise_fma(g2, w0xy[u2 + t], mx0);
                    mq0 = __builtin_elementwise_fma(g2, w0qp[u2 + t], mq0);
                    mx1 = __builtin_elementwise_fma(g2, w1xy[u2 + t], mx1);
                    mq1 = __builtin_elementwise_fma(g2, w1qp[u2 + t], mq1);
                }
            }
            ssim_add(mx0, mq0);
            ssim_add(mx1, mq1);
        }
    }

    // ---- block reduction -> one partial per block ----
#pragma unroll
    for (int off = 32; off > 0; off >>= 1) accum += __shfl_down(accum, off, 64);
    const int wave = tid >> 6;
    const int lane = tid & 63;
    if (lane == 0) rbuf[wave] = accum;
    __syncthreads();
    if (tid == 0) partial[bid] = rbuf[0] + rbuf[1] + rbuf[2] + rbuf[3];
}

extern "C" void kernel_launch(void* const* d_in, const int* in_sizes, int n_in,
                              void* d_out, int out_size, void* d_ws, size_t ws_size,
                              hipStream_t stream) {
    const float* img1 = (const float*)d_in[0];
    const float* img2 = (const float*)d_in[1];
    float* out = (float*)d_out;
    float* partial = (float*)d_ws;   // NBLOCKS floats (4 KB)

    GW gw;
    {
        double gd[11];
        double ssum = 0.0;
        for (int i = 0; i < 11; ++i) {
            const double t = (double)(i - 5);
            gd[i] = exp(-(t * t) / 4.5);
            ssum += gd[i];
        }
        for (int i = 0; i < 11; ++i) gw.g[i] = (float)(gd[i] / ssum);
    }

    ssim3d_kernel<<<NBLOCKS, 256, 0, stream>>>(img1, img2, partial, gw);
    finalize_kernel<<<1, 256, 0, stream>>>(partial, out);
}

// Round 3
// 221.636 us; speedup vs baseline: 3.3912x; 1.0197x over previous
//
#include <hip/hip_runtime.h>
#include <math.h>

typedef float v2f __attribute__((ext_vector_type(2)));

namespace {

constexpr int C_DIM = 4;
constexpr int D_DIM = 64;
constexpr int H_DIM = 160;
constexpr int W_DIM = 160;

// 16x16 tile: 256 output positions -> exactly 1 per thread. This keeps the
// per-thread D-window state to ONE output (28 v2f, ~48 live regs) so the
// kernel fits in <=80 VGPR -> 3 waves/SIMD (256-reg/SIMD budget, measured:
// V=104 -> 2 blocks/CU, V=64 -> 4 blocks/CU).
constexpr int TH = 16;
constexpr int TW = 16;
constexpr int HALO = 5;
constexpr int EH = 26;
constexpr int EW = 26;
constexpr int XST = 27;          // v2f stride of xy rows (odd)
constexpr int MST = 17;          // float4 stride of mid rows (odd)
constexpr int NPIX = EH * EW;    // 676

constexpr int TILES_W = 10;      // 160/16
constexpr int TPC = 100;         // 10x10 tiles per (b,c)
constexpr int D_SPLIT = 2;       // 32 output slices per block
constexpr int DCH = D_DIM / D_SPLIT;
constexpr int NBLOCKS = D_SPLIT * 2 * C_DIM * TPC;  // 1600

constexpr float C1f = 1e-4f;
constexpr float C2f = 9e-4f;
constexpr float INV_N = 1.0f / (2.0f * 64.0f * 160.0f * 160.0f);

struct GW { float g[11]; };

}  // namespace

__global__ void finalize_kernel(const float* __restrict__ partial,
                                float* __restrict__ out) {
    const int tid = threadIdx.x;
    const int c = tid >> 6;        // one wave per channel
    const int lane = tid & 63;
    float s = 0.0f;
#pragma unroll
    for (int r = 0; r < D_SPLIT * 2; ++r) {
        const int base = (r * C_DIM + c) * TPC;
        s += partial[base + lane];
        if (lane < TPC - 64) s += partial[base + 64 + lane];
    }
#pragma unroll
    for (int off = 32; off > 0; off >>= 1) s += __shfl_down(s, off, 64);
    if (lane == 0 && c < C_DIM) out[c] = 1.0f - s * INV_N;
}

// NOTE (measured R0-R2): effective VGPR budget is ~256/SIMD.
//   (256,2) -> V=104 -> 2 blocks/CU (occ 20%); (256,4) -> V capped 64 ->
//   spills the D-windows (2.5 GB scratch, 5x slower). Target: V<=80 via
//   1-output-per-thread structure + (256,3) -> 3 blocks/CU.
__global__ __launch_bounds__(256, 3) void ssim3d_kernel(
    const float* __restrict__ img1, const float* __restrict__ img2,
    float* __restrict__ partial, GW gwp) {

    const int bid = blockIdx.x;
    const int tile = bid % TPC;
    const int c = (bid / TPC) % C_DIM;
    const int rest = bid / (TPC * C_DIM);
    const int b = rest & 1;
    const int dh = rest >> 1;
    const int h0 = (tile / TILES_W) * TH;
    const int w0 = (tile % TILES_W) * TW;

    // D chunk: outputs d in [d_lo, d_lo+DCH). Staged slices [s_base, s_hi],
    // s_base rounded down to a multiple of 4 so slice phase u == s mod 4.
    const int d_lo = dh * DCH;
    const int s_base = (d_lo == 0) ? 0 : ((d_lo - HALO) & ~3);
    const int s_hi = min(D_DIM - 1, d_lo + DCH - 1 + HALO);
    const bool has_tail = (d_lo + DCH == D_DIM);

    const long planeHW = (long)H_DIM * W_DIM;
    const long volbase = (long)(b * C_DIM + c) * D_DIM * planeHW;
    const long org = volbase + (long)(h0 - HALO) * W_DIM + (w0 - HALO);
    const float* __restrict__ p1 = img1 + org;
    const float* __restrict__ p2 = img2 + org;

    const bool interior = (h0 >= HALO) && (h0 + TH + HALO <= H_DIM) &&
                          (w0 >= HALO) && (w0 + TW + HALO <= W_DIM);

    // ---- LDS (both stages double-buffered -> 1 barrier per slice) ----
    __shared__ v2f    xy[2][EH][XST];    // interleaved (x,y), b64   (11.2 KB)
    __shared__ float4 mid[2][EH][MST];   // W-conv partials, b128    (14.1 KB)
    __shared__ float  rbuf[4];

    const int tid = threadIdx.x;

    // ---- staging decode (3 positions/thread, 676 px). Persist only the
    // offsets (6 ints) + ok bitmask to keep register pressure minimal.
    int off_[3], loff_[3];
    unsigned okmask = 0;
#pragma unroll
    for (int k = 0; k < 3; ++k) {
        const int e = tid + k * 256;
        const int hh = e / EW;
        const int ww = e - hh * EW;
        off_[k] = hh * W_DIM + ww;
        loff_[k] = hh * XST + ww;
        const int gh = h0 - HALO + hh;
        const int gw = w0 - HALO + ww;
        if (((unsigned)gh < (unsigned)H_DIM) &&
            ((unsigned)gw < (unsigned)W_DIM))
            okmask |= 1u << k;
    }
    const bool live2 = (tid < NPIX - 512);   // k=2 position exists

    auto fetch_slice = [&](int s, v2f lv[3]) {
        const long sb = (long)s * planeHW;
#pragma unroll
        for (int k = 0; k < 3; ++k) {
            lv[k] = (v2f){0.0f, 0.0f};
            const bool live = (k < 2) || live2;
            if (live && (interior || ((okmask >> k) & 1u))) {
                const long gi = sb + off_[k];
                lv[k].x = p1[gi];
                lv[k].y = p2[gi];
            }
        }
    };
    auto commit_slice = [&](int buf, const v2f lv[3]) {
        v2f* base = &xy[buf][0][0];
#pragma unroll
        for (int k = 0; k < 3; ++k) {
            const bool live = (k < 2) || live2;
            if (live) base[loff_[k]] = lv[k];
        }
    };

    // ---- wconv: 208 workers, 2 adjacent W-outputs each, 12-tap stream
    const bool wactive = (tid < 208);
    const int whh = tid % 26;
    const int wg2 = (tid / 26) * 2;   // 0,2,...,14

    auto wconv = [&](int cur) {
        v2f a0 = {0.f,0.f}, a1 = {0.f,0.f};
        v2f q0 = {0.f,0.f}, q1 = {0.f,0.f};
#pragma unroll
        for (int t = 0; t < 12; ++t) {
            const v2f xv = xy[cur][whh][wg2 + t];
            v2f qp;
            qp.x = fmaf(xv.x, xv.x, xv.y * xv.y);  // x^2 + y^2
            qp.y = xv.x * xv.y;                    // x*y
            if (t <= 10) {
                const v2f g2 = {gwp.g[t], gwp.g[t]};
                a0 = __builtin_elementwise_fma(g2, xv, a0);
                q0 = __builtin_elementwise_fma(g2, qp, q0);
            }
            if (t >= 1) {
                const v2f g2 = {gwp.g[t-1], gwp.g[t-1]};
                a1 = __builtin_elementwise_fma(g2, xv, a1);
                q1 = __builtin_elementwise_fma(g2, qp, q1);
            }
        }
        mid[cur][whh][wg2]     = make_float4(a0.x, a0.y, q0.x, q0.y);
        mid[cur][whh][wg2 + 1] = make_float4(a1.x, a1.y, q1.x, q1.y);
    };

    // ---- hconv: ALL 256 threads, exactly 1 output position each
    const int hw = tid & 15;          // w position
    const int hy = tid >> 4;          // h position

    float accum = 0.0f;
    auto ssim_add = [&](v2f mxy, v2f mqp) {
        const float m1 = mxy.x, m2 = mxy.y;
        const float q = mqp.x, pp = mqp.y;
        const float m1s = m1 * m1;
        const float m2s = m2 * m2;
        const float m12 = m1 * m2;
        const float spp = q - m1s - m2s;
        const float s12 = pp - m12;
        const float num = (2.0f * m12 + C1f) * (2.0f * s12 + C2f);
        const float den = (m1s + m2s + C1f) * (spp + C2f);
        accum = fmaf(num, __builtin_amdgcn_rcpf(den), accum);
    };

    // ONE D-window: 14 slots, insert at 10+u, consume [u..u+10], shift by 4
    // per 4 slices. Static indices only.
    v2f w0xy[14], w0qp[14];
#pragma unroll
    for (int i = 0; i < 14; ++i) {
        w0xy[i] = (v2f){0.f, 0.f}; w0qp[i] = (v2f){0.f, 0.f};
    }

    // prologue: slice s_base -> xy[0]  (s_base % 4 == 0 -> buffer 0)
    {
        v2f lv[3];
        fetch_slice(s_base, lv);
        commit_slice(0, lv);
    }
    __syncthreads();

    for (int sb = s_base; sb <= s_hi; sb += 4) {   // sb mult of 4 -> s&1==u&1
#pragma unroll
        for (int u = 0; u < 4; ++u) {
            const int s = sb + u;
            if (s > s_hi) break;          // block-uniform
            v2f lv[3];
            const bool have_next = (s + 1 <= s_hi);
            if (have_next) fetch_slice(s + 1, lv);
            if (wactive) wconv(u & 1);
            if (have_next) commit_slice((u + 1) & 1, lv);
            __syncthreads();
            {
                // H-conv: 1 output from 11 b128 reads
                v2f zx = {0.f,0.f}, zq = {0.f,0.f};
#pragma unroll
                for (int t = 0; t < 11; ++t) {
                    const float4 m = mid[u & 1][hy + t][hw];
                    const v2f ma = {m.x, m.y};
                    const v2f mb = {m.z, m.w};
                    const v2f g2 = {gwp.g[t], gwp.g[t]};
                    zx = __builtin_elementwise_fma(g2, ma, zx);
                    zq = __builtin_elementwise_fma(g2, mb, zq);
                }
                w0xy[10 + u] = zx; w0qp[10 + u] = zq;
                if (s >= d_lo + HALO) {   // output d = s-5 (>= d_lo)
                    v2f mx0 = {0.f,0.f}, mq0 = {0.f,0.f};
#pragma unroll
                    for (int t = 0; t < 11; ++t) {
                        const v2f g2 = {gwp.g[t], gwp.g[t]};
                        mx0 = __builtin_elementwise_fma(g2, w0xy[u + t], mx0);
                        mq0 = __builtin_elementwise_fma(g2, w0qp[u + t], mq0);
                    }
                    ssim_add(mx0, mq0);
                }
            }
        }
        {
            // shift window by 4
#pragma unroll
            for (int k = 0; k < 10; ++k) {
                w0xy[k] = w0xy[k + 4]; w0qp[k] = w0qp[k + 4];
            }
        }
    }

    // epilogue (only the chunk reaching d=D_DIM-1): outputs d = 59..63;
    // window holds slices 54+k at slot k (0..9)
    if (has_tail) {
#pragma unroll
        for (int i = 10; i < 14; ++i) {
            w0xy[i] = (v2f){0.f, 0.f}; w0qp[i] = (v2f){0.f, 0.f};
        }
#pragma unroll
        for (int u2 = 0; u2 < 5; ++u2) {   // output d = 59 + u2
            v2f mx0 = {0.f,0.f}, mq0 = {0.f,0.f};
#pragma unroll
            for (int t = 0; t < 11; ++t) {
                if (u2 + t <= 13) {        // static guard; dropped taps zero
                    const v2f g2 = {gwp.g[t], gwp.g[t]};
                    mx0 = __builtin_elementwise_fma(g2, w0xy[u2 + t], mx0);
                    mq0 = __builtin_elementwise_fma(g2, w0qp[u2 + t], mq0);
                }
            }
            ssim_add(mx0, mq0);
        }
    }

    // ---- block reduction -> one partial per block ----
#pragma unroll
    for (int off = 32; off > 0; off >>= 1) accum += __shfl_down(accum, off, 64);
    const int wave = tid >> 6;
    const int lane = tid & 63;
    if (lane == 0) rbuf[wave] = accum;
    __syncthreads();
    if (tid == 0) partial[bid] = rbuf[0] + rbuf[1] + rbuf[2] + rbuf[3];
}

extern "C" void kernel_launch(void* const* d_in, const int* in_sizes, int n_in,
                              void* d_out, int out_size, void* d_ws, size_t ws_size,
                              hipStream_t stream) {
    const float* img1 = (const float*)d_in[0];
    const float* img2 = (const float*)d_in[1];
    float* out = (float*)d_out;
    float* partial = (float*)d_ws;   // NBLOCKS floats (6.4 KB)

    GW gw;
    {
        double gd[11];
        double ssum = 0.0;
        for (int i = 0; i < 11; ++i) {
            const double t = (double)(i - 5);
            gd[i] = exp(-(t * t) / 4.5);
            ssum += gd[i];
        }
        for (int i = 0; i < 11; ++i) gw.g[i] = (float)(gd[i] / ssum);
    }

    ssim3d_kernel<<<NBLOCKS, 256, 0, stream>>>(img1, img2, partial, gw);
    finalize_kernel<<<1, 256, 0, stream>>>(partial, out);
}

// Round 4
// 218.666 us; speedup vs baseline: 3.4372x; 1.0136x over previous
//
#include <hip/hip_runtime.h>
#include <math.h>
#include <stdint.h>
#include <string.h>

typedef float v2f __attribute__((ext_vector_type(2)));

namespace {

constexpr int C_DIM = 4;
constexpr int D_DIM = 64;
constexpr int H_DIM = 160;
constexpr int W_DIM = 160;

// 16x16 tile, 1 output/thread, FULL D per block (D_SPLIT=1):
// 800 blocks < 1024 resident slots (4 blocks/CU @ V<=64) -> single round,
// zero D-halo re-staging (-17% total work vs D_SPLIT=2).
constexpr int TH = 16;
constexpr int TW = 16;
constexpr int HALO = 5;
constexpr int EH = 26;
constexpr int EW = 26;
constexpr int QST = 27;          // float4 stride of xyqp rows (odd)
constexpr int MST = 17;          // float4 stride of mid rows (odd)
constexpr int NPIX = EH * EW;    // 676

constexpr int TILES_W = 10;      // 160/16
constexpr int TPC = 100;         // 10x10 tiles per (b,c)
constexpr int NBLOCKS = 2 * C_DIM * TPC;   // 800

constexpr float C1f = 1e-4f;
constexpr float C2f = 9e-4f;
constexpr float INV_N = 1.0f / (2.0f * 64.0f * 160.0f * 160.0f);

// Each double holds the SAME fp32 Gaussian weight in both halves -> loads
// into an aligned SGPR pair -> legal single-SGPR-operand v_pk_fma_f32.
struct GW { double gd[11]; };

}  // namespace

// Packed f32 FMA: acc = x * {g,g} + acc. MI355X's 157.3 TF fp32 is the
// packed pipe; scalar v_fma_f32 runs at half rate. The compiler won't form
// v_pk_fma_f32 with a scalar weight on its own (would need {g,g} VGPR
// pairs); the SGPR-pair trick makes it free.
static __device__ __forceinline__ void pk_fma(v2f& acc, v2f x, double g) {
    asm("v_pk_fma_f32 %0, %1, %2, %0" : "+v"(acc) : "v"(x), "s"(g));
}

__global__ void finalize_kernel(const float* __restrict__ partial,
                                float* __restrict__ out) {
    const int tid = threadIdx.x;
    const int c = tid >> 6;        // one wave per channel
    const int lane = tid & 63;
    float s = 0.0f;
#pragma unroll
    for (int b = 0; b < 2; ++b) {
        const int base = (b * C_DIM + c) * TPC;
        s += partial[base + lane];
        if (lane < TPC - 64) s += partial[base + 64 + lane];
    }
#pragma unroll
    for (int off = 32; off > 0; off >>= 1) s += __shfl_down(s, off, 64);
    if (lane == 0 && c < C_DIM) out[c] = 1.0f - s * INV_N;
}

// Measured R0-R3: effective VGPR budget is 256/SIMD. Natural pressure of the
// 1-output structure is ~60 -> (256,4) cap at 64 is safe (R1's spill needed
// 104+) and guarantees 4 waves/SIMD.
__global__ __launch_bounds__(256, 4) void ssim3d_kernel(
    const float* __restrict__ img1, const float* __restrict__ img2,
    float* __restrict__ partial, GW gwp) {

    const int bid = blockIdx.x;
    const int tile = bid % TPC;
    const int c = (bid / TPC) % C_DIM;
    const int b = bid / (TPC * C_DIM);
    const int h0 = (tile / TILES_W) * TH;
    const int w0 = (tile % TILES_W) * TW;

    const long planeHW = (long)H_DIM * W_DIM;
    const long volbase = (long)(b * C_DIM + c) * D_DIM * planeHW;
    const long org = volbase + (long)(h0 - HALO) * W_DIM + (w0 - HALO);
    const float* __restrict__ p1 = img1 + org;
    const float* __restrict__ p2 = img2 + org;

    const bool interior = (h0 >= HALO) && (h0 + TH + HALO <= H_DIM) &&
                          (w0 >= HALO) && (w0 + TW + HALO <= W_DIM);

    // ---- LDS (both stages double-buffered -> 1 barrier per slice) ----
    // xyqp: {x, y, x^2+y^2, x*y} per pixel -> qp computed ONCE per pixel
    // at staging instead of ~12x per pixel inside wconv taps.
    __shared__ float4 xyqp[2][EH][QST];   // 22.5 KB
    __shared__ float4 mid[2][EH][MST];    // 14.1 KB
    __shared__ float  rbuf[4];

    const int tid = threadIdx.x;

    // ---- staging decode (3 positions/thread, 676 px) ----
    int off_[3], loff_[3];
    unsigned okmask = 0;
#pragma unroll
    for (int k = 0; k < 3; ++k) {
        const int e = tid + k * 256;
        const int hh = e / EW;
        const int ww = e - hh * EW;
        off_[k] = hh * W_DIM + ww;
        loff_[k] = hh * QST + ww;
        const int gh = h0 - HALO + hh;
        const int gw = w0 - HALO + ww;
        if (((unsigned)gh < (unsigned)H_DIM) &&
            ((unsigned)gw < (unsigned)W_DIM))
            okmask |= 1u << k;
    }
    const bool live2 = (tid < NPIX - 512);   // k=2 position exists

    auto fetch_slice = [&](int s, v2f lv[3]) {
        const long sb = (long)s * planeHW;
#pragma unroll
        for (int k = 0; k < 3; ++k) {
            lv[k] = (v2f){0.0f, 0.0f};
            const bool live = (k < 2) || live2;
            if (live && (interior || ((okmask >> k) & 1u))) {
                const long gi = sb + off_[k];
                lv[k].x = p1[gi];
                lv[k].y = p2[gi];
            }
        }
    };
    auto commit_slice = [&](int buf, const v2f lv[3]) {
        float4* base = &xyqp[buf][0][0];
#pragma unroll
        for (int k = 0; k < 3; ++k) {
            const bool live = (k < 2) || live2;
            if (live) {
                const float x = lv[k].x, y = lv[k].y;
                base[loff_[k]] = make_float4(x, y, fmaf(x, x, y * y), x * y);
            }
        }
    };

    // ---- wconv: 208 workers, 2 adjacent W-outputs each, 12-tap stream
    const bool wactive = (tid < 208);
    const int whh = tid % 26;
    const int wg2 = (tid / 26) * 2;   // 0,2,...,14

    auto wconv = [&](int cur) {
        v2f a0 = {0.f,0.f}, a1 = {0.f,0.f};
        v2f q0 = {0.f,0.f}, q1 = {0.f,0.f};
#pragma unroll
        for (int t = 0; t < 12; ++t) {
            const float4 m = xyqp[cur][whh][wg2 + t];
            const v2f xv = {m.x, m.y};
            const v2f qp = {m.z, m.w};
            if (t <= 10) {
                pk_fma(a0, xv, gwp.gd[t]);
                pk_fma(q0, qp, gwp.gd[t]);
            }
            if (t >= 1) {
                pk_fma(a1, xv, gwp.gd[t-1]);
                pk_fma(q1, qp, gwp.gd[t-1]);
            }
        }
        mid[cur][whh][wg2]     = make_float4(a0.x, a0.y, q0.x, q0.y);
        mid[cur][whh][wg2 + 1] = make_float4(a1.x, a1.y, q1.x, q1.y);
    };

    // ---- hconv: ALL 256 threads, exactly 1 output position each
    const int hw = tid & 15;          // w position
    const int hy = tid >> 4;          // h position

    float accum = 0.0f;
    auto ssim_add = [&](v2f mxy, v2f mqp) {
        const float m1 = mxy.x, m2 = mxy.y;
        const float q = mqp.x, pp = mqp.y;
        const float m1s = m1 * m1;
        const float m2s = m2 * m2;
        const float m12 = m1 * m2;
        const float spp = q - m1s - m2s;
        const float s12 = pp - m12;
        const float num = (2.0f * m12 + C1f) * (2.0f * s12 + C2f);
        const float den = (m1s + m2s + C1f) * (spp + C2f);
        accum = fmaf(num, __builtin_amdgcn_rcpf(den), accum);
    };

    // ONE D-window: 14 slots, insert at 10+u, consume [u..u+10], shift by 4
    // per 4 slices. Static indices only.
    v2f w0xy[14], w0qp[14];
#pragma unroll
    for (int i = 0; i < 14; ++i) {
        w0xy[i] = (v2f){0.f, 0.f}; w0qp[i] = (v2f){0.f, 0.f};
    }

    // prologue: slice 0 -> xyqp[0]
    {
        v2f lv[3];
        fetch_slice(0, lv);
        commit_slice(0, lv);
    }
    __syncthreads();

    for (int sb = 0; sb < D_DIM; sb += 4) {   // sb mult of 4 -> s&1 == u&1
#pragma unroll
        for (int u = 0; u < 4; ++u) {
            const int s = sb + u;
            v2f lv[3];
            const bool have_next = (s + 1 < D_DIM);
            if (have_next) fetch_slice(s + 1, lv);
            if (wactive) wconv(u & 1);
            if (have_next) commit_slice((u + 1) & 1, lv);
            __syncthreads();
            {
                // H-conv: 1 output from 11 b128 reads
                v2f zx = {0.f,0.f}, zq = {0.f,0.f};
#pragma unroll
                for (int t = 0; t < 11; ++t) {
                    const float4 m = mid[u & 1][hy + t][hw];
                    const v2f ma = {m.x, m.y};
                    const v2f mb = {m.z, m.w};
                    pk_fma(zx, ma, gwp.gd[t]);
                    pk_fma(zq, mb, gwp.gd[t]);
                }
                w0xy[10 + u] = zx; w0qp[10 + u] = zq;
                if (s >= HALO) {   // output d = s-5
                    v2f mx0 = {0.f,0.f}, mq0 = {0.f,0.f};
#pragma unroll
                    for (int t = 0; t < 11; ++t) {
                        pk_fma(mx0, w0xy[u + t], gwp.gd[t]);
                        pk_fma(mq0, w0qp[u + t], gwp.gd[t]);
                    }
                    ssim_add(mx0, mq0);
                }
            }
        }
        {
            // shift window by 4
#pragma unroll
            for (int k = 0; k < 10; ++k) {
                w0xy[k] = w0xy[k + 4]; w0qp[k] = w0qp[k + 4];
            }
        }
    }

    // epilogue: outputs d = 59..63; window holds slices 54+k at slot k (0..9)
    {
#pragma unroll
        for (int i = 10; i < 14; ++i) {
            w0xy[i] = (v2f){0.f, 0.f}; w0qp[i] = (v2f){0.f, 0.f};
        }
#pragma unroll
        for (int u2 = 0; u2 < 5; ++u2) {   // output d = 59 + u2
            v2f mx0 = {0.f,0.f}, mq0 = {0.f,0.f};
#pragma unroll
            for (int t = 0; t < 11; ++t) {
                if (u2 + t <= 13) {        // static guard; dropped taps zero
                    pk_fma(mx0, w0xy[u2 + t], gwp.gd[t]);
                    pk_fma(mq0, w0qp[u2 + t], gwp.gd[t]);
                }
            }
            ssim_add(mx0, mq0);
        }
    }

    // ---- block reduction -> one partial per block ----
#pragma unroll
    for (int off = 32; off > 0; off >>= 1) accum += __shfl_down(accum, off, 64);
    const int wave = tid >> 6;
    const int lane = tid & 63;
    if (lane == 0) rbuf[wave] = accum;
    __syncthreads();
    if (tid == 0) partial[bid] = rbuf[0] + rbuf[1] + rbuf[2] + rbuf[3];
}

extern "C" void kernel_launch(void* const* d_in, const int* in_sizes, int n_in,
                              void* d_out, int out_size, void* d_ws, size_t ws_size,
                              hipStream_t stream) {
    const float* img1 = (const float*)d_in[0];
    const float* img2 = (const float*)d_in[1];
    float* out = (float*)d_out;
    float* partial = (float*)d_ws;   // NBLOCKS floats (3.2 KB)

    GW gw;
    {
        double gd[11];
        double ssum = 0.0;
        for (int i = 0; i < 11; ++i) {
            const double t = (double)(i - 5);
            gd[i] = exp(-(t * t) / 4.5);
            ssum += gd[i];
        }
        for (int i = 0; i < 11; ++i) {
            const float gf = (float)(gd[i] / ssum);
            uint32_t ub;
            memcpy(&ub, &gf, 4);
            const uint64_t up = ((uint64_t)ub << 32) | ub;   // {g, g}
            memcpy(&gw.gd[i], &up, 8);
        }
    }

    ssim3d_kernel<<<NBLOCKS, 256, 0, stream>>>(img1, img2, partial, gw);
    finalize_kernel<<<1, 256, 0, stream>>>(partial, out);
}